// Round 1
// baseline (226.504 us; speedup 1.0000x reference)
//
#include <hip/hip_runtime.h>

// Blur = UpFirDn2D(up=2, dn=2, k=4x4 outer([1,3,3,1])/16).
// Index algebra: only odd taps (t=1,3) hit non-zero samples of the
// zero-interleaved input, so the whole op collapses to a 2x2 stencil:
//   out[i][j] = F[1][1]*x[i][j] + F[1][3]*x[i][j+1]
//             + F[3][1]*x[i+1][j] + F[3][3]*x[i+1][j+1]
// with x out-of-range treated as 0. Output shape == input shape.
// Memory-bound: ~268 MB traffic -> ~43 us floor at 6.3 TB/s.

constexpr int NB = 8, NC = 256, H = 128, W = 128;

__global__ __launch_bounds__(256) void blur_kernel(
    const float* __restrict__ x,
    const float* __restrict__ filt,
    float* __restrict__ out)
{
    int t = blockIdx.x * blockDim.x + threadIdx.x;
    // total float4s = (NB*NC) * H * (W/4) = 2048 * 128 * 32 = 8388608
    int q   = t & 31;          // float4 index within row (j = 4*q)
    int r   = (t >> 5) & 127;  // row
    int img = t >> 12;         // b*NC + c
    int c   = img & (NC - 1);

    // 4x4 filter row-major; taps (1,1),(1,3),(3,1),(3,3) -> 5,7,13,15
    const float* fb = filt + c * 16;
    float w11 = fb[5], w13 = fb[7], w31 = fb[13], w33 = fb[15];

    const float* row0 = x + ((size_t)img * H + r) * W + (q << 2);
    float4 a = *(const float4*)row0;
    float aR = (q < 31) ? row0[4] : 0.0f;

    float4 b = make_float4(0.f, 0.f, 0.f, 0.f);
    float bR = 0.0f;
    if (r < H - 1) {
        const float* row1 = row0 + W;
        b  = *(const float4*)row1;
        bR = (q < 31) ? row1[4] : 0.0f;
    }

    float4 o;
    o.x = w11 * a.x + w13 * a.y + w31 * b.x + w33 * b.y;
    o.y = w11 * a.y + w13 * a.z + w31 * b.y + w33 * b.z;
    o.z = w11 * a.z + w13 * a.w + w31 * b.z + w33 * b.w;
    o.w = w11 * a.w + w13 * aR  + w31 * b.w + w33 * bR;

    *(float4*)(out + ((size_t)img * H + r) * W + (q << 2)) = o;
}

extern "C" void kernel_launch(void* const* d_in, const int* in_sizes, int n_in,
                              void* d_out, int out_size, void* d_ws, size_t ws_size,
                              hipStream_t stream)
{
    const float* x    = (const float*)d_in[0];
    const float* filt = (const float*)d_in[1];
    float* out        = (float*)d_out;

    const int total_f4 = NB * NC * H * (W / 4);   // 8388608
    const int block = 256;
    const int grid  = total_f4 / block;           // 32768

    blur_kernel<<<grid, block, 0, stream>>>(x, filt, out);
}

// Round 2
// 222.357 us; speedup vs baseline: 1.0187x; 1.0187x over previous
//
#include <hip/hip_runtime.h>

// Blur = UpFirDn2D(up=2, dn=2, k=4x4 outer([1,3,3,1])/16) collapses to a
// 2x2 stencil (only odd taps hit non-zero interleaved samples):
//   out[i][j] = F[1][1]*x[i][j] + F[1][3]*x[i][j+1]
//             + F[3][1]*x[i+1][j] + F[3][3]*x[i+1][j+1],  OOB x = 0.
// Memory-bound: ~268 MB traffic -> ~43 us floor at 6.3 TB/s.
//
// R1: minimize VMEM issue. Neighbor (j+4) taps come from lane+1 via shuffle
// (lanes 0..31 = row r, lanes 32..63 = row r+1, so lane+1 holds the next
// float4 of the same row; q==31 masked to 0). Weight loads scalarized via
// readfirstlane (channel is wave-uniform). VMEM/thread: 9 -> 3.

constexpr int NB = 8, NC = 256, H = 128, W = 128;

__global__ __launch_bounds__(256) void blur_kernel(
    const float* __restrict__ x,
    const float* __restrict__ filt,
    float* __restrict__ out)
{
    int t = blockIdx.x * blockDim.x + threadIdx.x;
    // total float4s = (NB*NC) * H * (W/4) = 8388608
    int q   = t & 31;          // float4 index within row (j = 4*q)
    int r   = (t >> 5) & 127;  // row (lanes 0-31: even r, lanes 32-63: r+1)
    int img = t >> 12;         // b*NC + c  (wave-uniform: 4096 threads/img)
    int c   = img & (NC - 1);

    // channel is wave-uniform -> force SGPR address -> s_load for weights
    int cu = __builtin_amdgcn_readfirstlane(c);
    const float* fb = filt + cu * 16;
    float w11 = fb[5], w13 = fb[7], w31 = fb[13], w33 = fb[15];

    const float* row0 = x + ((size_t)img * H + r) * W + (q << 2);
    float4 a = *(const float4*)row0;

    float4 b = make_float4(0.f, 0.f, 0.f, 0.f);
    if (r < H - 1) b = *(const float4*)(row0 + W);

    // j+4 neighbor elements from the next lane (same row for q<31)
    float aR = __shfl_down(a.x, 1);
    float bR = __shfl_down(b.x, 1);
    if (q == 31) { aR = 0.0f; bR = 0.0f; }

    float4 o;
    o.x = w11 * a.x + w13 * a.y + w31 * b.x + w33 * b.y;
    o.y = w11 * a.y + w13 * a.z + w31 * b.y + w33 * b.z;
    o.z = w11 * a.z + w13 * a.w + w31 * b.z + w33 * b.w;
    o.w = w11 * a.w + w13 * aR  + w31 * b.w + w33 * bR;

    *(float4*)(out + ((size_t)img * H + r) * W + (q << 2)) = o;
}

extern "C" void kernel_launch(void* const* d_in, const int* in_sizes, int n_in,
                              void* d_out, int out_size, void* d_ws, size_t ws_size,
                              hipStream_t stream)
{
    const float* x    = (const float*)d_in[0];
    const float* filt = (const float*)d_in[1];
    float* out        = (float*)d_out;

    const int total_f4 = NB * NC * H * (W / 4);   // 8388608
    const int block = 256;
    const int grid  = total_f4 / block;           // 32768

    blur_kernel<<<grid, block, 0, stream>>>(x, filt, out);
}